// Round 20
// baseline (355.261 us; speedup 1.0000x reference)
//
#include <hip/hip_runtime.h>

#define T_ 5
#define C_ 3
#define H_ 128
#define W_ 128
#define HW_ (H_*W_)
#define WS_ 9
#define K_ 10
#define QN_ (T_*H_*W_)   // 81920
#define NSLOTS 1024
#define TOTAL_SEL (QN_ * 2 * K_)   // 1638400
#define R_ 15            // staged region side (window 9 + patch 7 - 1)
#define RS_ 17           // padded row stride in PIXELS (8B f16x4 each)
#define RRS_ (R_*RS_)    // 255 pixels per region

typedef _Float16 h4 __attribute__((ext_vector_type(4)));
typedef _Float16 h2 __attribute__((ext_vector_type(2)));

#define CFENCE() __asm__ __volatile__("" ::: "memory")

__device__ __forceinline__ h2 as_h2(unsigned u) { return __builtin_bit_cast(h2, u); }

#if __has_builtin(__builtin_amdgcn_fdot2)
__device__ __forceinline__ float FDOT2(h2 a, h2 b, float c) {
    return __builtin_amdgcn_fdot2(a, b, c, false);
}
#else
__device__ __forceinline__ float FDOT2(h2 a, h2 b, float c) {
    return fmaf((float)a.x, (float)b.x, fmaf((float)a.y, (float)b.y, c));
}
#endif

__device__ __forceinline__ int clampi(int v, int hi) {
    return v < 0 ? 0 : (v > hi ? hi : v);
}
__device__ __forceinline__ int mbcnt64(unsigned long long m) {
    return __builtin_amdgcn_mbcnt_hi((unsigned)(m >> 32),
           __builtin_amdgcn_mbcnt_lo((unsigned)m, 0));
}

// Border (slow) pack: nibble j = clamp(clamp(cen+w4-4)+j-3) - mn  (double clamp).
// REQUIRES mn = clamp(clamp(cen-4)-3): every nibble provably in [0,14] (R14 fix).
__device__ __forceinline__ unsigned mkpack_axis(int cen, int w4, int mn) {
    const int b = clampi(cen + w4 - 4, H_ - 1);
    unsigned r = 0;
    #pragma unroll
    for (int j = 0; j < 7; ++j)
        r |= (unsigned)(clampi(b + j - 3, H_ - 1) - mn) << (4 * j);
    return r;
}
// Interior fast pack (no clamp when 7 <= cen <= 120): nibble j = w4+j
__device__ __forceinline__ unsigned mkpack_int(int w4) {
    return (unsigned)w4 * 0x1111111u + 0x6543210u;
}

// One wave per query, both directions fused; all LDS wave-private, no
// __syncthreads. R17-R19 post-mortem: DS *issue slots* (~270/wave) are the
// limiter, not conflicts (conflict swings of +/-50% moved dur <2%). R20 =
// R16 + ONE change: pass-1 query values via v_readlane from the register
// pack (index dy*7+dx is wave-uniform -> SGPR broadcast) — removes the 49
// Q broadcast DS reads/wave; VALU has ~70% slack. R17 bundled this with
// RS=19 whose 20480B LDS block broke 8-blocks/CU — deconfounded here.
__global__ __launch_bounds__(256, 8) void dnls_main(
    const float* __restrict__ noisy,
    const float* __restrict__ deno,
    const float* __restrict__ fflow,
    const float* __restrict__ bflow,
    float* __restrict__ acc)
{
    __shared__ h4 sR[4][2 * RRS_];       // regions s0|s1: (rgb, sumsq) f16; deno then noisy
    __shared__ uint2 sQ[4][49];          // query patch: packed f16 (-2qx,-2qy | -2qz, 1.0)
    __shared__ unsigned sSlot[4][20];    // compacted top-k keys

    const int wave = threadIdx.x >> 6;
    const int lane = threadIdx.x & 63;
    const int q = blockIdx.x * 4 + wave;

    const int qt = q / HW_;
    const int qr = q - qt * HW_;
    const int qy = qr >> 7;
    const int qx = qr & 127;

    const int ct0 = (qt + 1 < T_) ? qt + 1 : T_ - 1;
    const int ct1 = (qt - 1 > 0) ? qt - 1 : 0;

    const int fidx = (qt * 2 * H_ + qy) * W_ + qx;
    const int cen_x0 = qx + (int)rintf(fflow[fidx]);
    const int cen_y0 = qy + (int)rintf(fflow[fidx + HW_]);
    const int cen_x1 = qx + (int)rintf(bflow[fidx]);
    const int cen_y1 = qy + (int)rintf(bflow[fidx + HW_]);

    const bool iy0 = (cen_y0 >= 7) && (cen_y0 <= H_ - 8);
    const bool ix0 = (cen_x0 >= 7) && (cen_x0 <= W_ - 8);
    const bool iy1 = (cen_y1 >= 7) && (cen_y1 <= H_ - 8);
    const bool ix1 = (cen_x1 >= 7) && (cen_x1 <= W_ - 8);

    // ---- defensive slot prefill: huge distance (mask kills), window 0 ----
    if (lane < 20) sSlot[wave][lane] = 0x7F000000u;

    // ---- query patch -> register pack (lane o<49) + LDS copy; qss uniform ----
    uint2 qpreg; qpreg.x = 0; qpreg.y = 0;
    float ss = 0.f;
    if (lane < 49) {
        const int dy = lane / 7 - 3;
        const int dx = lane - (lane / 7) * 7 - 3;
        const int yy = clampi(qy + dy, H_ - 1);
        const int xx = clampi(qx + dx, W_ - 1);
        const float* p = deno + (size_t)qt * C_ * HW_ + yy * W_ + xx;
        const float a = p[0], b = p[HW_], c = p[2 * HW_];
        ss = fmaf(a, a, fmaf(b, b, c * c));
        h2 q01; q01.x = (_Float16)(-2.f * a); q01.y = (_Float16)(-2.f * b);
        h2 q23; q23.x = (_Float16)(-2.f * c); q23.y = (_Float16)1.0f;
        qpreg.x = __builtin_bit_cast(unsigned, q01);
        qpreg.y = __builtin_bit_cast(unsigned, q23);
        sQ[wave][lane] = qpreg;
    }
    #pragma unroll
    for (int off = 32; off >= 1; off >>= 1) ss += __shfl_xor(ss, off, 64);
    const float qss = ss;

    // region bases: min double-clamped row/col over all (w4, j)  [R14 fix]
    const int rmin0 = clampi(clampi(cen_y0 - 4, H_ - 1) - 3, H_ - 1);
    const int cmin0 = clampi(clampi(cen_x0 - 4, W_ - 1) - 3, W_ - 1);
    const int rmin1 = clampi(clampi(cen_y1 - 4, H_ - 1) - 3, H_ - 1);
    const int cmin1 = clampi(clampi(cen_x1 - 4, W_ - 1) - 3, W_ - 1);
    const float* cfrm0 = deno  + (size_t)ct0 * C_ * HW_;
    const float* cfrm1 = deno  + (size_t)ct1 * C_ * HW_;
    const float* nfrm0 = noisy + (size_t)ct0 * C_ * HW_;
    const float* nfrm1 = noisy + (size_t)ct1 * C_ * HW_;

    // ---- stage both regions (deno @ ct0/ct1) as f16x4 (rgb, sumsq) ----
    for (int i = lane; i < 2 * R_ * R_; i += 64) {
        const int reg = (i >= R_ * R_);
        const int rem = i - reg * (R_ * R_);
        const int ry = rem / R_;
        const int rx = rem - ry * R_;
        int sy = (reg ? rmin1 : rmin0) + ry; if (sy > H_ - 1) sy = H_ - 1;
        int sx = (reg ? cmin1 : cmin0) + rx; if (sx > W_ - 1) sx = W_ - 1;
        const int gi = sy * W_ + sx;
        const float* f = reg ? cfrm1 : cfrm0;
        const float a = f[gi], b = f[HW_ + gi], c = f[2 * HW_ + gi];
        const float w = fmaf(a, a, fmaf(b, b, c * c));
        h4 v; v[0] = (_Float16)a; v[1] = (_Float16)b; v[2] = (_Float16)c; v[3] = (_Float16)w;
        sR[wave][reg * RRS_ + ry * RS_ + rx] = v;
    }
    CFENCE();   // staging writes precede all region reads in program order

    const char* R0 = (const char*)&sR[wave][0];
    const char* R1 = (const char*)&sR[wave][RRS_];
    const uint2* Q2 = &sQ[wave][0];

    // ---- pass 1: window w = lane (0..63), both directions ----
    const int wy4p1 = lane / 9;
    const int wx4p1 = lane - 9 * wy4p1;
    const unsigned rpA = iy0 ? mkpack_int(wy4p1) : mkpack_axis(cen_y0, wy4p1, rmin0);
    const unsigned cpA = ix0 ? mkpack_int(wx4p1) : mkpack_axis(cen_x0, wx4p1, cmin0);
    const unsigned rpB = iy1 ? mkpack_int(wy4p1) : mkpack_axis(cen_y1, wy4p1, rmin1);
    const unsigned cpB = ix1 ? mkpack_int(wx4p1) : mkpack_axis(cen_x1, wx4p1, cmin1);

    int colA[7], colB[7];   // byte offsets, dy-invariant (dx fully unrolled)
    #pragma unroll
    for (int dx = 0; dx < 7; ++dx) {
        colA[dx] = (int)((cpA >> (4 * dx)) & 15) * 8;
        colB[dx] = (int)((cpB >> (4 * dx)) & 15) * 8;
    }
    float uAlo = 0.f, uAhi = 0.f;   // s0: two parallel dot chains
    float uBlo = 0.f, uBhi = 0.f;   // s1
    #pragma unroll 1
    for (int dy = 0; dy < 7; ++dy) {
        const char* rowA = R0 + ((rpA >> (4 * dy)) & 15) * (RS_ * 8);
        const char* rowB = R1 + ((rpB >> (4 * dy)) & 15) * (RS_ * 8);
        const int ob = dy * 7;
        #pragma unroll
        for (int dx = 0; dx < 7; ++dx) {
            // query via v_readlane (wave-uniform index): no DS issue slot
            const h2 q01 = as_h2(__builtin_amdgcn_readlane(qpreg.x, ob + dx));
            const h2 q23 = as_h2(__builtin_amdgcn_readlane(qpreg.y, ob + dx));
            const uint2 cuA = *(const uint2*)(rowA + colA[dx]);
            const uint2 cuB = *(const uint2*)(rowB + colB[dx]);
            uAlo = FDOT2(as_h2(cuA.x), q01, uAlo);
            uAhi = FDOT2(as_h2(cuA.y), q23, uAhi);     // -2qz*cz + sumsq*1.0
            uBlo = FDOT2(as_h2(cuB.x), q01, uBlo);
            uBhi = FDOT2(as_h2(cuB.y), q23, uBhi);
        }
    }
    const float d1_0 = fmaxf(qss + (uAlo + uAhi), 0.f);
    const float d1_1 = fmaxf(qss + (uBlo + uBhi), 0.f);

    // ---- pass 2: windows 64..80, 3 lanes per window ----
    float d2_0 = 0.f, d2_1 = 0.f;
    const int w2   = 64 + lane / 3;          // valid for lane < 51
    const int part = lane - (lane / 3) * 3;
    if (lane < 51) {
        const int wy4 = w2 / 9;              // 7 or 8
        const int wx4 = w2 - 9 * wy4;
        const unsigned rp2A = iy0 ? mkpack_int(wy4) : mkpack_axis(cen_y0, wy4, rmin0);
        const unsigned cp2A = ix0 ? mkpack_int(wx4) : mkpack_axis(cen_x0, wx4, cmin0);
        const unsigned rp2B = iy1 ? mkpack_int(wy4) : mkpack_axis(cen_y1, wy4, rmin1);
        const unsigned cp2B = ix1 ? mkpack_int(wx4) : mkpack_axis(cen_x1, wx4, cmin1);
        float tAlo = 0.f, tAhi = 0.f, tBlo = 0.f, tBhi = 0.f;
        int dyi = 0, dxi = part;
        #pragma unroll 1
        for (int o = part; o < 49; o += 3) {
            const uint2 qp = Q2[o];          // lane-varying o: stays LDS
            const h2 q01 = as_h2(qp.x), q23 = as_h2(qp.y);
            const uint2 cuA = *(const uint2*)(R0 + ((rp2A >> (4 * dyi)) & 15) * (RS_ * 8)
                                                 + ((cp2A >> (4 * dxi)) & 15) * 8);
            const uint2 cuB = *(const uint2*)(R1 + ((rp2B >> (4 * dyi)) & 15) * (RS_ * 8)
                                                 + ((cp2B >> (4 * dxi)) & 15) * 8);
            tAlo = FDOT2(as_h2(cuA.x), q01, tAlo);
            tAhi = FDOT2(as_h2(cuA.y), q23, tAhi);
            tBlo = FDOT2(as_h2(cuB.x), q01, tBlo);
            tBhi = FDOT2(as_h2(cuB.y), q23, tBhi);
            dxi += 3; if (dxi >= 7) { dxi -= 7; ++dyi; }
        }
        d2_0 = tAlo + tAhi;
        d2_1 = tBlo + tBhi;
    }
    const int base3 = lane * 3;
    const int g0 = base3 < 64 ? base3 : 0;
    const int g1 = base3 + 1 < 64 ? base3 + 1 : 0;
    const int g2 = base3 + 2 < 64 ? base3 + 2 : 0;
    const float dd0 = fmaxf(qss + __shfl(d2_0, g0) + __shfl(d2_0, g1) + __shfl(d2_0, g2), 0.f);
    const float dd1 = fmaxf(qss + __shfl(d2_1, g0) + __shfl(d2_1, g1) + __shfl(d2_1, g2), 0.f);

    CFENCE();   // all deno-region reads precede the noisy restage
    // ---- restage with noisy (f16x4, .w = sumsq); geometry recomputed ----
    for (int i = lane; i < 2 * R_ * R_; i += 64) {
        const int reg = (i >= R_ * R_);
        const int rem = i - reg * (R_ * R_);
        const int ry = rem / R_;
        const int rx = rem - ry * R_;
        int sy = (reg ? rmin1 : rmin0) + ry; if (sy > H_ - 1) sy = H_ - 1;
        int sx = (reg ? cmin1 : cmin0) + rx; if (sx > W_ - 1) sx = W_ - 1;
        const int gi = sy * W_ + sx;
        const float* f = reg ? nfrm1 : nfrm0;
        const float a = f[gi], b = f[HW_ + gi], c = f[2 * HW_ + gi];
        const float w = fmaf(a, a, fmaf(b, b, c * c));
        h4 v; v[0] = (_Float16)a; v[1] = (_Float16)b; v[2] = (_Float16)c; v[3] = (_Float16)w;
        sR[wave][reg * RRS_ + ry * RS_ + rx] = v;
    }
    CFENCE();   // restage writes precede refine reads

    // ---- top-10 per direction via bitwise rank-select (VALU/SALU only) ----
    const unsigned kA0 = (__float_as_uint(d1_0) & 0xFFFFFF80u) | (unsigned)lane;
    const unsigned kA1 = (__float_as_uint(d1_1) & 0xFFFFFF80u) | (unsigned)lane;
    const unsigned kB0 = (lane < 17)
        ? ((__float_as_uint(dd0) & 0xFFFFFF80u) | (unsigned)(64 + lane)) : 0xFFFFFFFFu;
    const unsigned kB1 = (lane < 17)
        ? ((__float_as_uint(dd1) & 0xFFFFFF80u) | (unsigned)(64 + lane)) : 0xFFFFFFFFu;

    unsigned tau0 = 0, tau1 = 0;
    #pragma unroll
    for (int b = 30; b >= 0; --b) {
        const unsigned t0v = tau0 | (1u << b);
        const unsigned t1v = tau1 | (1u << b);
        const int c0 = __popcll(__ballot(kA0 < t0v)) + __popcll(__ballot(kB0 < t0v));
        const int c1 = __popcll(__ballot(kA1 < t1v)) + __popcll(__ballot(kB1 < t1v));
        if (c0 <= 9) tau0 = t0v;
        if (c1 <= 9) tau1 = t1v;
    }
    {
        const bool sA0 = (kA0 <= tau0), sB0 = (kB0 <= tau0);
        const unsigned long long mA0 = __ballot(sA0), mB0 = __ballot(sB0);
        if (sA0) sSlot[wave][mbcnt64(mA0)] = kA0;
        if (sB0) sSlot[wave][__popcll(mA0) + mbcnt64(mB0)] = kB0;
        const bool sA1 = (kA1 <= tau1), sB1 = (kB1 <= tau1);
        const unsigned long long mA1 = __ballot(sA1), mB1 = __ballot(sB1);
        if (sA1) sSlot[wave][10 + mbcnt64(mA1)] = kA1;
        if (sB1) sSlot[wave][10 + __popcll(mA1) + mbcnt64(mB1)] = kB1;
    }
    CFENCE();   // slot writes precede slot read

    const int sel = lane % 20;
    const unsigned myKey = sSlot[wave][sel];   // per-wave DS in-order
    const int   myW = (int)(myKey & 0x7Fu);
    const float myD = __uint_as_float(myKey & 0xFFFFFF80u);
    const int   wSafe = (myW <= 80) ? myW : 0;   // fail-safe addressing

    // ---- refine: dref = qss + sum(n.w - 2 q.n); mask per lane ----
    float partial = 0.f;
    if (lane < 60) {
        const int s1sel = (sel >= 10);
        const int ceny = s1sel ? cen_y1 : cen_y0;
        const int cenx = s1sel ? cen_x1 : cen_x0;
        const int rmr  = s1sel ? rmin1 : rmin0;
        const int cmr  = s1sel ? cmin1 : cmin0;
        const bool iyr = s1sel ? iy1 : iy0;
        const bool ixr = s1sel ? ix1 : ix0;
        const char* Nb = s1sel ? R1 : R0;
        const int wy4 = wSafe / 9;
        const int wx4 = wSafe - 9 * wy4;
        const unsigned rpR = iyr ? mkpack_int(wy4) : mkpack_axis(ceny, wy4, rmr);
        const unsigned cpR = ixr ? mkpack_int(wx4) : mkpack_axis(cenx, wx4, cmr);
        const int rpart = lane / 20;   // 0..2
        float tlo = 0.f, thi = 0.f;
        int dyi = 0, dxi = rpart;
        #pragma unroll 1
        for (int o = rpart; o < 49; o += 3) {
            const uint2 qp = Q2[o];
            const uint2 nu = *(const uint2*)(Nb + ((rpR >> (4 * dyi)) & 15) * (RS_ * 8)
                                                + ((cpR >> (4 * dxi)) & 15) * 8);
            tlo = FDOT2(as_h2(nu.x), as_h2(qp.x), tlo);
            thi = FDOT2(as_h2(nu.y), as_h2(qp.y), thi);
            dxi += 3; if (dxi >= 7) { dxi -= 7; ++dyi; }
        }
        partial = tlo + thi;
        if (rpart == 0) partial += qss;   // qss once per selection
        // mask: d0/147 < 0.5; also kill any corrupt/sentinel selection
        if (!(myD < 73.5f) || myW != wSafe) partial = 0.f;
    }
    #pragma unroll
    for (int off = 32; off >= 1; off >>= 1)
        partial += __shfl_xor(partial, off, 64);

    if (lane == 0)
        atomicAdd(&acc[q & (NSLOTS - 1)], partial * (1.0f / (float)TOTAL_SEL));
}

__global__ __launch_bounds__(64) void dnls_reduce(const float* __restrict__ acc,
                                                  float* __restrict__ out)
{
    const int lane = threadIdx.x;
    float v = 0.f;
    for (int i = lane; i < NSLOTS; i += 64) v += acc[i];
    #pragma unroll
    for (int off = 32; off >= 1; off >>= 1)
        v += __shfl_xor(v, off, 64);
    if (lane == 0) out[0] = v;
}

extern "C" void kernel_launch(void* const* d_in, const int* in_sizes, int n_in,
                              void* d_out, int out_size, void* d_ws, size_t ws_size,
                              hipStream_t stream) {
    const float* noisy = (const float*)d_in[0];
    const float* deno  = (const float*)d_in[2];
    const float* fflow = (const float*)d_in[3];
    const float* bflow = (const float*)d_in[4];
    float* out = (float*)d_out;
    float* acc = (float*)d_ws;

    hipMemsetAsync(acc, 0, NSLOTS * sizeof(float), stream);

    const int nblocks = QN_ / 4;   // one wave per query, 4 waves/block
    dnls_main<<<nblocks, 256, 0, stream>>>(noisy, deno, fflow, bflow, acc);
    dnls_reduce<<<1, 64, 0, stream>>>(acc, out);
}

// Round 21
// 332.080 us; speedup vs baseline: 1.0698x; 1.0698x over previous
//
#include <hip/hip_runtime.h>

#define T_ 5
#define C_ 3
#define H_ 128
#define W_ 128
#define HW_ (H_*W_)
#define WS_ 9
#define K_ 10
#define QN_ (T_*H_*W_)   // 81920
#define NSLOTS 1024
#define TOTAL_SEL (QN_ * 2 * K_)   // 1638400
#define R_ 15            // staged region side (window 9 + patch 7 - 1)
#define RS_ 17           // padded row stride in PIXELS (8B f16x4 each)
#define RRS_ (R_*RS_)    // 255 pixels per region

typedef _Float16 h4 __attribute__((ext_vector_type(4)));
typedef _Float16 h2 __attribute__((ext_vector_type(2)));

#define CFENCE() __asm__ __volatile__("" ::: "memory")

__device__ __forceinline__ h2 as_h2(unsigned u) { return __builtin_bit_cast(h2, u); }

#if __has_builtin(__builtin_amdgcn_fdot2)
__device__ __forceinline__ float FDOT2(h2 a, h2 b, float c) {
    return __builtin_amdgcn_fdot2(a, b, c, false);
}
#else
__device__ __forceinline__ float FDOT2(h2 a, h2 b, float c) {
    return fmaf((float)a.x, (float)b.x, fmaf((float)a.y, (float)b.y, c));
}
#endif

__device__ __forceinline__ int clampi(int v, int hi) {
    return v < 0 ? 0 : (v > hi ? hi : v);
}
__device__ __forceinline__ int mbcnt64(unsigned long long m) {
    return __builtin_amdgcn_mbcnt_hi((unsigned)(m >> 32),
           __builtin_amdgcn_mbcnt_lo((unsigned)m, 0));
}

// Border (slow) pack: nibble j = clamp(clamp(cen+w4-4)+j-3) - mn  (double clamp).
// REQUIRES mn = clamp(clamp(cen-4)-3): every nibble provably in [0,14] (R14 fix —
// the old clamp(cen-7) went negative for cen>=132, corrupting the pack -> OOB).
__device__ __forceinline__ unsigned mkpack_axis(int cen, int w4, int mn) {
    const int b = clampi(cen + w4 - 4, H_ - 1);
    unsigned r = 0;
    #pragma unroll
    for (int j = 0; j < 7; ++j)
        r |= (unsigned)(clampi(b + j - 3, H_ - 1) - mn) << (4 * j);
    return r;
}
// Interior fast pack (no clamp when 7 <= cen <= 120): nibble j = w4+j
__device__ __forceinline__ unsigned mkpack_int(int w4) {
    return (unsigned)w4 * 0x1111111u + 0x6543210u;
}

// FINAL (R16 structure, session best: ~302 µs dispatch, 10.8x vs baseline).
// One wave per query, both directions fused; LDS wave-private, no
// __syncthreads. Key design points, each counter-verified:
//  - f16x4 (rgb,sumsq) region staging + SSD as qss + dot(-2q,c) via
//    v_dot2_f32_f16 (R15: -40% VALU);
//  - (256,8): 8 blocks/CU = 32 waves/CU HW cap (R16: occupancy 52->79%);
//  - uniform-address LDS Q reads are broadcast ~free — readlane swap
//    REGRESSED 7% (R20); bank-conflict swings of +/-50% move dur <2%
//    (R17-R19): the plateau is gather issue+latency, structural to the
//    81-window flow-shifted stencil.
__global__ __launch_bounds__(256, 8) void dnls_main(
    const float* __restrict__ noisy,
    const float* __restrict__ deno,
    const float* __restrict__ fflow,
    const float* __restrict__ bflow,
    float* __restrict__ acc)
{
    __shared__ h4 sR[4][2 * RRS_];       // regions s0|s1: (rgb, sumsq) f16; deno then noisy
    __shared__ uint2 sQ[4][49];          // query patch: packed f16 (-2qx,-2qy | -2qz, 1.0)
    __shared__ unsigned sSlot[4][20];    // compacted top-k keys

    const int wave = threadIdx.x >> 6;
    const int lane = threadIdx.x & 63;
    const int q = blockIdx.x * 4 + wave;

    const int qt = q / HW_;
    const int qr = q - qt * HW_;
    const int qy = qr >> 7;
    const int qx = qr & 127;

    const int ct0 = (qt + 1 < T_) ? qt + 1 : T_ - 1;
    const int ct1 = (qt - 1 > 0) ? qt - 1 : 0;

    const int fidx = (qt * 2 * H_ + qy) * W_ + qx;
    const int cen_x0 = qx + (int)rintf(fflow[fidx]);
    const int cen_y0 = qy + (int)rintf(fflow[fidx + HW_]);
    const int cen_x1 = qx + (int)rintf(bflow[fidx]);
    const int cen_y1 = qy + (int)rintf(bflow[fidx + HW_]);

    const bool iy0 = (cen_y0 >= 7) && (cen_y0 <= H_ - 8);
    const bool ix0 = (cen_x0 >= 7) && (cen_x0 <= W_ - 8);
    const bool iy1 = (cen_y1 >= 7) && (cen_y1 <= H_ - 8);
    const bool ix1 = (cen_x1 >= 7) && (cen_x1 <= W_ - 8);

    // ---- defensive slot prefill: huge distance (mask kills), window 0 ----
    if (lane < 20) sSlot[wave][lane] = 0x7F000000u;

    // ---- query patch -> packed f16 LDS; qss = sum q^2 (wave-uniform) ----
    float ss = 0.f;
    if (lane < 49) {
        const int dy = lane / 7 - 3;
        const int dx = lane - (lane / 7) * 7 - 3;
        const int yy = clampi(qy + dy, H_ - 1);
        const int xx = clampi(qx + dx, W_ - 1);
        const float* p = deno + (size_t)qt * C_ * HW_ + yy * W_ + xx;
        const float a = p[0], b = p[HW_], c = p[2 * HW_];
        ss = fmaf(a, a, fmaf(b, b, c * c));
        h2 q01; q01.x = (_Float16)(-2.f * a); q01.y = (_Float16)(-2.f * b);
        h2 q23; q23.x = (_Float16)(-2.f * c); q23.y = (_Float16)1.0f;
        uint2 qp;
        qp.x = __builtin_bit_cast(unsigned, q01);
        qp.y = __builtin_bit_cast(unsigned, q23);
        sQ[wave][lane] = qp;
    }
    #pragma unroll
    for (int off = 32; off >= 1; off >>= 1) ss += __shfl_xor(ss, off, 64);
    const float qss = ss;

    // region bases: min double-clamped row/col over all (w4, j)  [R14 fix]
    const int rmin0 = clampi(clampi(cen_y0 - 4, H_ - 1) - 3, H_ - 1);
    const int cmin0 = clampi(clampi(cen_x0 - 4, W_ - 1) - 3, W_ - 1);
    const int rmin1 = clampi(clampi(cen_y1 - 4, H_ - 1) - 3, H_ - 1);
    const int cmin1 = clampi(clampi(cen_x1 - 4, W_ - 1) - 3, W_ - 1);
    const float* cfrm0 = deno  + (size_t)ct0 * C_ * HW_;
    const float* cfrm1 = deno  + (size_t)ct1 * C_ * HW_;
    const float* nfrm0 = noisy + (size_t)ct0 * C_ * HW_;
    const float* nfrm1 = noisy + (size_t)ct1 * C_ * HW_;

    // ---- stage both regions (deno @ ct0/ct1) as f16x4 (rgb, sumsq) ----
    for (int i = lane; i < 2 * R_ * R_; i += 64) {
        const int reg = (i >= R_ * R_);
        const int rem = i - reg * (R_ * R_);
        const int ry = rem / R_;
        const int rx = rem - ry * R_;
        int sy = (reg ? rmin1 : rmin0) + ry; if (sy > H_ - 1) sy = H_ - 1;
        int sx = (reg ? cmin1 : cmin0) + rx; if (sx > W_ - 1) sx = W_ - 1;
        const int gi = sy * W_ + sx;
        const float* f = reg ? cfrm1 : cfrm0;
        const float a = f[gi], b = f[HW_ + gi], c = f[2 * HW_ + gi];
        const float w = fmaf(a, a, fmaf(b, b, c * c));
        h4 v; v[0] = (_Float16)a; v[1] = (_Float16)b; v[2] = (_Float16)c; v[3] = (_Float16)w;
        sR[wave][reg * RRS_ + ry * RS_ + rx] = v;
    }
    CFENCE();   // staging writes precede all region reads in program order

    const char* R0 = (const char*)&sR[wave][0];
    const char* R1 = (const char*)&sR[wave][RRS_];
    const uint2* Q2 = &sQ[wave][0];

    // ---- pass 1: window w = lane (0..63), both directions ----
    const int wy4p1 = lane / 9;
    const int wx4p1 = lane - 9 * wy4p1;
    const unsigned rpA = iy0 ? mkpack_int(wy4p1) : mkpack_axis(cen_y0, wy4p1, rmin0);
    const unsigned cpA = ix0 ? mkpack_int(wx4p1) : mkpack_axis(cen_x0, wx4p1, cmin0);
    const unsigned rpB = iy1 ? mkpack_int(wy4p1) : mkpack_axis(cen_y1, wy4p1, rmin1);
    const unsigned cpB = ix1 ? mkpack_int(wx4p1) : mkpack_axis(cen_x1, wx4p1, cmin1);

    int colA[7], colB[7];   // byte offsets, dy-invariant (dx fully unrolled)
    #pragma unroll
    for (int dx = 0; dx < 7; ++dx) {
        colA[dx] = (int)((cpA >> (4 * dx)) & 15) * 8;
        colB[dx] = (int)((cpB >> (4 * dx)) & 15) * 8;
    }
    float uAlo = 0.f, uAhi = 0.f;   // s0: two parallel dot chains
    float uBlo = 0.f, uBhi = 0.f;   // s1
    #pragma unroll 1
    for (int dy = 0; dy < 7; ++dy) {
        const char* rowA = R0 + ((rpA >> (4 * dy)) & 15) * (RS_ * 8);
        const char* rowB = R1 + ((rpB >> (4 * dy)) & 15) * (RS_ * 8);
        const int ob = dy * 7;
        #pragma unroll
        for (int dx = 0; dx < 7; ++dx) {
            const uint2 qp = Q2[ob + dx];              // uniform addr: broadcast
            const h2 q01 = as_h2(qp.x), q23 = as_h2(qp.y);
            const uint2 cuA = *(const uint2*)(rowA + colA[dx]);
            const uint2 cuB = *(const uint2*)(rowB + colB[dx]);
            uAlo = FDOT2(as_h2(cuA.x), q01, uAlo);
            uAhi = FDOT2(as_h2(cuA.y), q23, uAhi);     // -2qz*cz + sumsq*1.0
            uBlo = FDOT2(as_h2(cuB.x), q01, uBlo);
            uBhi = FDOT2(as_h2(cuB.y), q23, uBhi);
        }
    }
    const float d1_0 = fmaxf(qss + (uAlo + uAhi), 0.f);
    const float d1_1 = fmaxf(qss + (uBlo + uBhi), 0.f);

    // ---- pass 2: windows 64..80, 3 lanes per window ----
    float d2_0 = 0.f, d2_1 = 0.f;
    const int w2   = 64 + lane / 3;          // valid for lane < 51
    const int part = lane - (lane / 3) * 3;
    if (lane < 51) {
        const int wy4 = w2 / 9;              // 7 or 8
        const int wx4 = w2 - 9 * wy4;
        const unsigned rp2A = iy0 ? mkpack_int(wy4) : mkpack_axis(cen_y0, wy4, rmin0);
        const unsigned cp2A = ix0 ? mkpack_int(wx4) : mkpack_axis(cen_x0, wx4, cmin0);
        const unsigned rp2B = iy1 ? mkpack_int(wy4) : mkpack_axis(cen_y1, wy4, rmin1);
        const unsigned cp2B = ix1 ? mkpack_int(wx4) : mkpack_axis(cen_x1, wx4, cmin1);
        float tAlo = 0.f, tAhi = 0.f, tBlo = 0.f, tBhi = 0.f;
        int dyi = 0, dxi = part;
        #pragma unroll 1
        for (int o = part; o < 49; o += 3) {
            const uint2 qp = Q2[o];          // lane-varying o: stays LDS
            const h2 q01 = as_h2(qp.x), q23 = as_h2(qp.y);
            const uint2 cuA = *(const uint2*)(R0 + ((rp2A >> (4 * dyi)) & 15) * (RS_ * 8)
                                                 + ((cp2A >> (4 * dxi)) & 15) * 8);
            const uint2 cuB = *(const uint2*)(R1 + ((rp2B >> (4 * dyi)) & 15) * (RS_ * 8)
                                                 + ((cp2B >> (4 * dxi)) & 15) * 8);
            tAlo = FDOT2(as_h2(cuA.x), q01, tAlo);
            tAhi = FDOT2(as_h2(cuA.y), q23, tAhi);
            tBlo = FDOT2(as_h2(cuB.x), q01, tBlo);
            tBhi = FDOT2(as_h2(cuB.y), q23, tBhi);
            dxi += 3; if (dxi >= 7) { dxi -= 7; ++dyi; }
        }
        d2_0 = tAlo + tAhi;
        d2_1 = tBlo + tBhi;
    }
    const int base3 = lane * 3;
    const int g0 = base3 < 64 ? base3 : 0;
    const int g1 = base3 + 1 < 64 ? base3 + 1 : 0;
    const int g2 = base3 + 2 < 64 ? base3 + 2 : 0;
    const float dd0 = fmaxf(qss + __shfl(d2_0, g0) + __shfl(d2_0, g1) + __shfl(d2_0, g2), 0.f);
    const float dd1 = fmaxf(qss + __shfl(d2_1, g0) + __shfl(d2_1, g1) + __shfl(d2_1, g2), 0.f);

    CFENCE();   // all deno-region reads precede the noisy restage
    // ---- restage with noisy (f16x4, .w = sumsq); geometry recomputed ----
    for (int i = lane; i < 2 * R_ * R_; i += 64) {
        const int reg = (i >= R_ * R_);
        const int rem = i - reg * (R_ * R_);
        const int ry = rem / R_;
        const int rx = rem - ry * R_;
        int sy = (reg ? rmin1 : rmin0) + ry; if (sy > H_ - 1) sy = H_ - 1;
        int sx = (reg ? cmin1 : cmin0) + rx; if (sx > W_ - 1) sx = W_ - 1;
        const int gi = sy * W_ + sx;
        const float* f = reg ? nfrm1 : nfrm0;
        const float a = f[gi], b = f[HW_ + gi], c = f[2 * HW_ + gi];
        const float w = fmaf(a, a, fmaf(b, b, c * c));
        h4 v; v[0] = (_Float16)a; v[1] = (_Float16)b; v[2] = (_Float16)c; v[3] = (_Float16)w;
        sR[wave][reg * RRS_ + ry * RS_ + rx] = v;
    }
    CFENCE();   // restage writes precede refine reads

    // ---- top-10 per direction via bitwise rank-select (VALU/SALU only) ----
    const unsigned kA0 = (__float_as_uint(d1_0) & 0xFFFFFF80u) | (unsigned)lane;
    const unsigned kA1 = (__float_as_uint(d1_1) & 0xFFFFFF80u) | (unsigned)lane;
    const unsigned kB0 = (lane < 17)
        ? ((__float_as_uint(dd0) & 0xFFFFFF80u) | (unsigned)(64 + lane)) : 0xFFFFFFFFu;
    const unsigned kB1 = (lane < 17)
        ? ((__float_as_uint(dd1) & 0xFFFFFF80u) | (unsigned)(64 + lane)) : 0xFFFFFFFFu;

    unsigned tau0 = 0, tau1 = 0;
    #pragma unroll
    for (int b = 30; b >= 0; --b) {
        const unsigned t0v = tau0 | (1u << b);
        const unsigned t1v = tau1 | (1u << b);
        const int c0 = __popcll(__ballot(kA0 < t0v)) + __popcll(__ballot(kB0 < t0v));
        const int c1 = __popcll(__ballot(kA1 < t1v)) + __popcll(__ballot(kB1 < t1v));
        if (c0 <= 9) tau0 = t0v;
        if (c1 <= 9) tau1 = t1v;
    }
    {
        const bool sA0 = (kA0 <= tau0), sB0 = (kB0 <= tau0);
        const unsigned long long mA0 = __ballot(sA0), mB0 = __ballot(sB0);
        if (sA0) sSlot[wave][mbcnt64(mA0)] = kA0;
        if (sB0) sSlot[wave][__popcll(mA0) + mbcnt64(mB0)] = kB0;
        const bool sA1 = (kA1 <= tau1), sB1 = (kB1 <= tau1);
        const unsigned long long mA1 = __ballot(sA1), mB1 = __ballot(sB1);
        if (sA1) sSlot[wave][10 + mbcnt64(mA1)] = kA1;
        if (sB1) sSlot[wave][10 + __popcll(mA1) + mbcnt64(mB1)] = kB1;
    }
    CFENCE();   // slot writes precede slot read

    const int sel = lane % 20;
    const unsigned myKey = sSlot[wave][sel];   // per-wave DS in-order
    const int   myW = (int)(myKey & 0x7Fu);
    const float myD = __uint_as_float(myKey & 0xFFFFFF80u);
    const int   wSafe = (myW <= 80) ? myW : 0;   // fail-safe addressing

    // ---- refine: dref = qss + sum(n.w - 2 q.n); mask per lane ----
    float partial = 0.f;
    if (lane < 60) {
        const int s1sel = (sel >= 10);
        const int ceny = s1sel ? cen_y1 : cen_y0;
        const int cenx = s1sel ? cen_x1 : cen_x0;
        const int rmr  = s1sel ? rmin1 : rmin0;
        const int cmr  = s1sel ? cmin1 : cmin0;
        const bool iyr = s1sel ? iy1 : iy0;
        const bool ixr = s1sel ? ix1 : ix0;
        const char* Nb = s1sel ? R1 : R0;
        const int wy4 = wSafe / 9;
        const int wx4 = wSafe - 9 * wy4;
        const unsigned rpR = iyr ? mkpack_int(wy4) : mkpack_axis(ceny, wy4, rmr);
        const unsigned cpR = ixr ? mkpack_int(wx4) : mkpack_axis(cenx, wx4, cmr);
        const int rpart = lane / 20;   // 0..2
        float tlo = 0.f, thi = 0.f;
        int dyi = 0, dxi = rpart;
        #pragma unroll 1
        for (int o = rpart; o < 49; o += 3) {
            const uint2 qp = Q2[o];
            const uint2 nu = *(const uint2*)(Nb + ((rpR >> (4 * dyi)) & 15) * (RS_ * 8)
                                                + ((cpR >> (4 * dxi)) & 15) * 8);
            tlo = FDOT2(as_h2(nu.x), as_h2(qp.x), tlo);
            thi = FDOT2(as_h2(nu.y), as_h2(qp.y), thi);
            dxi += 3; if (dxi >= 7) { dxi -= 7; ++dyi; }
        }
        partial = tlo + thi;
        if (rpart == 0) partial += qss;   // qss once per selection
        // mask: d0/147 < 0.5; also kill any corrupt/sentinel selection
        if (!(myD < 73.5f) || myW != wSafe) partial = 0.f;
    }
    #pragma unroll
    for (int off = 32; off >= 1; off >>= 1)
        partial += __shfl_xor(partial, off, 64);

    if (lane == 0)
        atomicAdd(&acc[q & (NSLOTS - 1)], partial * (1.0f / (float)TOTAL_SEL));
}

__global__ __launch_bounds__(64) void dnls_reduce(const float* __restrict__ acc,
                                                  float* __restrict__ out)
{
    const int lane = threadIdx.x;
    float v = 0.f;
    for (int i = lane; i < NSLOTS; i += 64) v += acc[i];
    #pragma unroll
    for (int off = 32; off >= 1; off >>= 1)
        v += __shfl_xor(v, off, 64);
    if (lane == 0) out[0] = v;
}

extern "C" void kernel_launch(void* const* d_in, const int* in_sizes, int n_in,
                              void* d_out, int out_size, void* d_ws, size_t ws_size,
                              hipStream_t stream) {
    const float* noisy = (const float*)d_in[0];
    const float* deno  = (const float*)d_in[2];
    const float* fflow = (const float*)d_in[3];
    const float* bflow = (const float*)d_in[4];
    float* out = (float*)d_out;
    float* acc = (float*)d_ws;

    hipMemsetAsync(acc, 0, NSLOTS * sizeof(float), stream);

    const int nblocks = QN_ / 4;   // one wave per query, 4 waves/block
    dnls_main<<<nblocks, 256, 0, stream>>>(noisy, deno, fflow, bflow, acc);
    dnls_reduce<<<1, 64, 0, stream>>>(acc, out);
}